// Round 10
// baseline (1399.175 us; speedup 1.0000x reference)
//
#include <hip/hip_runtime.h>
#include <math.h>

// Problem constants (B,N,C fixed by the reference setup).
#define BB 16
#define NN 2048
#define CC 64
#define TPB 256
#define MROWS 16          // pruned rows per block (4 waves x 4 rows)
#define RPW 4             // rows per wave
#define E_CONST 2.71828182845904523536f

// ---------------------------------------------------------------------------
// K_pre (fused): all 512 blocks zero their 16 KB slice of out (the A
// accumulator).  Blocks 0..BB-1 additionally: ballot-compaction for batch b,
// zero S[b,:], then build colM[b] (normalized kept cols, k-quad-minor) --
// fusing the old k_pre2 and saving a launch.
// ---------------------------------------------------------------------------
__global__ __launch_bounds__(TPB) void k_pre(const float* __restrict__ x,
                                             const float* __restrict__ keep,
                                             float* __restrict__ outz,
                                             float* __restrict__ S,
                                             int* __restrict__ cntP,
                                             int* __restrict__ cntK,
                                             int* __restrict__ listP,
                                             int* __restrict__ listK,
                                             float4* __restrict__ colM) {
    const int tid = threadIdx.x, lane = tid & 63;

    float4* o4 = (float4*)outz + (size_t)blockIdx.x * 1024;
    float4 z = {0.0f, 0.0f, 0.0f, 0.0f};
#pragma unroll
    for (int i = 0; i < 4; ++i) o4[i * TPB + tid] = z;

    const int b = blockIdx.x;
    if (b >= BB) return;

    __shared__ int cP, cK;
    if (tid == 0) { cP = 0; cK = 0; }
    __syncthreads();
    for (int i = tid; i < NN; i += TPB) S[b * NN + i] = 0.0f;
    const unsigned long long lt = (lane == 63) ? 0x7fffffffffffffffull
                                               : ((1ull << lane) - 1ull);
#pragma unroll
    for (int it = 0; it < NN / TPB; ++it) {
        int n = it * TPB + tid;
        bool kp = keep[b * NN + n] != 0.0f;
        unsigned long long mk = __ballot(kp);
        int nk = __popcll(mk);
        int bk = 0, bp = 0;
        if (lane == 0) {
            bk = atomicAdd(&cK, nk);
            bp = atomicAdd(&cP, 64 - nk);
        }
        bk = __shfl(bk, 0); bp = __shfl(bp, 0);
        int pk = __popcll(mk & lt);
        if (kp) listK[b * NN + bk + pk] = n;
        else    listP[b * NN + bp + (lane - pk)] = n;
    }
    __syncthreads();
    if (tid == 0) { cntP[b] = cP; cntK[b] = cK; }
    __syncthreads();

    // ---- build colM for this batch (old k_pre2, same-CU L1 serves listK) --
    const int K = cK;
    const float4* x4 = (const float4*)(x + (size_t)b * NN * CC);
#pragma unroll
    for (int it = 0; it < NN / TPB; ++it) {
        int colp = it * TPB + tid;
        bool ok = colp < K;
        int tok = ok ? listK[b * NN + colp] : 0;
        float4 v[16];
        float sq = 0.0f;
#pragma unroll
        for (int k4 = 0; k4 < 16; ++k4) {
            v[k4] = x4[(size_t)tok * 16 + k4];
            sq += v[k4].x * v[k4].x + v[k4].y * v[k4].y
                + v[k4].z * v[k4].z + v[k4].w * v[k4].w;
        }
        float iv = ok ? 1.0f / (sqrtf(sq) + 1e-6f) : 0.0f;
#pragma unroll
        for (int k4 = 0; k4 < 16; ++k4) {
            float4 w = v[k4];
            w.x *= iv; w.y *= iv; w.z *= iv; w.w *= iv;
            colM[((size_t)b * 16 + k4) * NN + colp] = w;
        }
    }
}

// ---------------------------------------------------------------------------
// K3: GEMM-argmax.  R9 tile (4 waves x 4 rows, acc[4][8]) + explicit col
// double-buffer.  Register budget: acc 32 + cva 32 + cvb 32 + rv 16 + addr
// ~= 127 under launch_bounds(256,3) cap (~170) -> all 8 prefetch loads stay
// in flight a full 128-FMA block ahead of their wait (R9's VGPR-60 schedule
// waited inside each k4).  R8's version of this spilled because acc was 64.
//  - 1-D grid, b = id&15 -> XCD pinning (FETCH 6.8 MB, L2-resident).
// ---------------------------------------------------------------------------
__global__ __launch_bounds__(TPB, 3) void k_argmax(
    const float* __restrict__ x,      // [B,N,C]
    const float4* __restrict__ colM,  // [B,16,N] float4
    const int*   __restrict__ cntP,
    const int*   __restrict__ cntK,
    const int*   __restrict__ listP,
    const int*   __restrict__ listK,
    float* __restrict__ S,            // [B,N]   zeroed by k_pre
    float* __restrict__ A) {          // [B,N,C] zeroed by k_pre; aliases d_out

    const int b    = blockIdx.x & 15;
    const int tile = blockIdx.x >> 4;
    const int P = cntP[b], K = cntK[b];
    const int base = tile * MROWS;
    if (base >= P) return;

    const int tid = threadIdx.x;
    const int wid = tid >> 6;
    const int lane = tid & 63;

    int rtok[RPW];
#pragma unroll
    for (int r = 0; r < RPW; ++r) {
        int rid = base + wid * RPW + r;
        int tok = (rid < P) ? listP[b * NN + rid] : 0;
        rtok[r] = __builtin_amdgcn_readfirstlane(tok);
    }
    const float4* x4 = (const float4*)(x + (size_t)b * NN * CC);
    const float4* cm = colM + (size_t)b * 16 * NN;

    float    tmax[RPW];
    unsigned msk[RPW];
#pragma unroll
    for (int r = 0; r < RPW; ++r) { tmax[r] = -3.0e38f; msk[r] = 0u; }

    const int ntiles = (K + 511) >> 9;              // dynamic, <= 4

    for (int t = 0; t < ntiles; ++t) {
        const int cstart = t * 512;
        const float4* cb = cm + cstart + lane;

        float acc[RPW][8];
#pragma unroll
        for (int r = 0; r < RPW; ++r)
#pragma unroll
            for (int j = 0; j < 8; ++j) acc[r][j] = 0.0f;

        float4 cva[8], cvb[8];
#pragma unroll
        for (int j = 0; j < 8; ++j) cva[j] = cb[j * 64];        // k4 = 0

#pragma unroll
        for (int kp = 0; kp < 8; ++kp) {
            const int ka = 2 * kp, kb = 2 * kp + 1;

            // prefetch odd k4 while computing even
#pragma unroll
            for (int j = 0; j < 8; ++j)
                cvb[j] = cb[(size_t)kb * NN + j * 64];
            {
                float4 rv[RPW];
#pragma unroll
                for (int r = 0; r < RPW; ++r)
                    rv[r] = x4[(size_t)rtok[r] * 16 + ka];
#pragma unroll
                for (int r = 0; r < RPW; ++r)
#pragma unroll
                    for (int j = 0; j < 8; ++j)
                        acc[r][j] = fmaf(rv[r].x, cva[j].x,
                                    fmaf(rv[r].y, cva[j].y,
                                    fmaf(rv[r].z, cva[j].z,
                                    fmaf(rv[r].w, cva[j].w, acc[r][j]))));
            }
            // prefetch next even k4 while computing odd
            if (kp < 7) {
#pragma unroll
                for (int j = 0; j < 8; ++j)
                    cva[j] = cb[(size_t)(ka + 2) * NN + j * 64];
            }
            {
                float4 rv[RPW];
#pragma unroll
                for (int r = 0; r < RPW; ++r)
                    rv[r] = x4[(size_t)rtok[r] * 16 + kb];
#pragma unroll
                for (int r = 0; r < RPW; ++r)
#pragma unroll
                    for (int j = 0; j < 8; ++j)
                        acc[r][j] = fmaf(rv[r].x, cvb[j].x,
                                    fmaf(rv[r].y, cvb[j].y,
                                    fmaf(rv[r].z, cvb[j].z,
                                    fmaf(rv[r].w, cvb[j].w, acc[r][j]))));
            }
        }

#pragma unroll
        for (int r = 0; r < RPW; ++r)
#pragma unroll
            for (int j = 0; j < 8; ++j) {
                int colp = cstart + j * 64 + lane;
                float s = (colp < K) ? acc[r][j] : -1.0e30f;
                unsigned bit = 1u << ((t << 3) | j);
                if (s > tmax[r])       { tmax[r] = s; msk[r] = bit; }
                else if (s == tmax[r])  msk[r] |= bit;
            }
    }

    // ---- edge emission: per wave, per valid row ----
    int nvr = P - base - wid * RPW;
    for (int r = 0; r < RPW; ++r) {
        if (r >= nvr) break;
        float m = tmax[r];
#pragma unroll
        for (int off = 32; off; off >>= 1) m = fmaxf(m, __shfl_xor(m, off, 64));
        int src = rtok[r];
        float xv = x[(size_t)(b * NN + src) * CC + lane];
        float sq = xv * xv;
#pragma unroll
        for (int off = 32; off; off >>= 1) sq += __shfl_xor(sq, off, 64);
        float ivr = 1.0f / (sqrtf(sq) + 1e-6f);
        float wgt = expf(m * ivr);
        unsigned long long bal = __ballot(tmax[r] == m && msk[r] != 0u);
        while (bal) {
            int sl = __ffsll(bal) - 1;
            bal &= bal - 1;
            unsigned mm = __shfl(msk[r], sl);
            while (mm) {
                int bit = __ffs(mm) - 1;
                mm &= mm - 1;
                int colp = ((bit >> 3) * 512) + ((bit & 7) * 64) + sl;
                int dst = listK[b * NN + colp];
                atomicAdd(&A[(size_t)(b * NN + dst) * CC + lane], wgt * xv);
                if (lane == 0) atomicAdd(&S[b * NN + dst], wgt);
            }
        }
    }
}

// ---------------------------------------------------------------------------
// K4: out = (e*x + A) / (e + S).  A aliases d_out (in-place), float4.
// ---------------------------------------------------------------------------
__global__ __launch_bounds__(TPB) void k_finalize(const float* __restrict__ x,
                                                  const float* __restrict__ S,
                                                  float* __restrict__ out) {
    int i = blockIdx.x * TPB + threadIdx.x;
    int row = i >> 4;
    float inv = 1.0f / (E_CONST + S[row]);
    float4 xv = ((const float4*)x)[i];
    float4 av = ((float4*)out)[i];
    float4 o;
    o.x = (xv.x * E_CONST + av.x) * inv;
    o.y = (xv.y * E_CONST + av.y) * inv;
    o.z = (xv.z * E_CONST + av.z) * inv;
    o.w = (xv.w * E_CONST + av.w) * inv;
    ((float4*)out)[i] = o;
}

// ---------------------------------------------------------------------------
extern "C" void kernel_launch(void* const* d_in, const int* in_sizes, int n_in,
                              void* d_out, int out_size, void* d_ws, size_t ws_size,
                              hipStream_t stream) {
    const float* x    = (const float*)d_in[0];
    const float* keep = (const float*)d_in[2];
    float* out = (float*)d_out;

    // ws: (reserved 128KB) | S 128KB | cnts 128B | listP 128KB | listK 128KB | colM 8MB
    char* ws = (char*)d_ws;
    float* S    = (float*)(ws + (128 << 10));
    int*   cntP = (int*)(ws + (256 << 10));
    int*   cntK = cntP + 16;
    int*   listP = (int*)(ws + (256 << 10) + 128);
    int*   listK = listP + BB * NN;
    float4* colM = (float4*)(ws + (1 << 20));

    k_pre<<<512, TPB, 0, stream>>>(x, keep, out, S, cntP, cntK,
                                   listP, listK, colM);

    // 1-D grid: b = id & 15 (XCD pinning), tile = id >> 4.
    k_argmax<<<(NN / MROWS) * BB, TPB, 0, stream>>>(x, colM, cntP, cntK,
                                                    listP, listK, S, out);

    k_finalize<<<(BB * NN * CC / 4) / TPB, TPB, 0, stream>>>(x, S, out);
}

// Round 11
// 237.579 us; speedup vs baseline: 5.8893x; 5.8893x over previous
//
#include <hip/hip_runtime.h>
#include <math.h>

// Problem constants (B,N,C fixed by the reference setup).
#define BB 16
#define NN 2048
#define CC 64
#define TPB 256
#define MROWS 16          // pruned rows per block; ALL 4 waves share them
#define E_CONST 2.71828182845904523536f

// ---------------------------------------------------------------------------
// K_pre: zero the A accumulator (d_out) everywhere; blocks 0..BB-1 also run
// ballot-based kept/pruned compaction for batch b and zero S[b,:].
// ---------------------------------------------------------------------------
__global__ __launch_bounds__(TPB) void k_pre(const float* __restrict__ keep,
                                             float* __restrict__ outz,
                                             float* __restrict__ S,
                                             int* __restrict__ cntP,
                                             int* __restrict__ cntK,
                                             int* __restrict__ listP,
                                             int* __restrict__ listK) {
    const int tid = threadIdx.x, lane = tid & 63;

    float4* o4 = (float4*)outz + (size_t)blockIdx.x * 1024;
    float4 z = {0.0f, 0.0f, 0.0f, 0.0f};
#pragma unroll
    for (int i = 0; i < 4; ++i) o4[i * TPB + tid] = z;

    const int b = blockIdx.x;
    if (b >= BB) return;

    __shared__ int cP, cK;
    if (tid == 0) { cP = 0; cK = 0; }
    __syncthreads();
    for (int i = tid; i < NN; i += TPB) S[b * NN + i] = 0.0f;
    const unsigned long long lt = (lane == 63) ? 0x7fffffffffffffffull
                                               : ((1ull << lane) - 1ull);
#pragma unroll
    for (int it = 0; it < NN / TPB; ++it) {
        int n = it * TPB + tid;
        bool kp = keep[b * NN + n] != 0.0f;
        unsigned long long mk = __ballot(kp);
        int nk = __popcll(mk);
        int bk = 0, bp = 0;
        if (lane == 0) {
            bk = atomicAdd(&cK, nk);
            bp = atomicAdd(&cP, 64 - nk);
        }
        bk = __shfl(bk, 0); bp = __shfl(bp, 0);
        int pk = __popcll(mk & lt);
        if (kp) listK[b * NN + bk + pk] = n;
        else    listP[b * NN + bp + (lane - pk)] = n;
    }
    __syncthreads();
    if (tid == 0) { cntP[b] = cP; cntK[b] = cK; }
}

// ---------------------------------------------------------------------------
// K_pre2: build colM[b][k4][colp] float4 = k-quad of kept column colp, scaled
// by its inverse L2 norm (computed inline); zeros for colp >= K.
// ---------------------------------------------------------------------------
__global__ __launch_bounds__(TPB) void k_pre2(const float* __restrict__ x,
                                              const int* __restrict__ cntK,
                                              const int* __restrict__ listK,
                                              float4* __restrict__ colM) {
    const int b = blockIdx.y;
    const int colp = blockIdx.x * TPB + threadIdx.x;
    const int K = cntK[b];
    bool ok = colp < K;
    int tok = ok ? listK[b * NN + colp] : 0;
    const float4* x4 = (const float4*)(x + (size_t)b * NN * CC);
    float4 v[16];
    float sq = 0.0f;
#pragma unroll
    for (int k4 = 0; k4 < 16; ++k4) {
        v[k4] = x4[(size_t)tok * 16 + k4];
        sq += v[k4].x * v[k4].x + v[k4].y * v[k4].y
            + v[k4].z * v[k4].z + v[k4].w * v[k4].w;
    }
    float iv = ok ? 1.0f / (sqrtf(sq) + 1e-6f) : 0.0f;
#pragma unroll
    for (int k4 = 0; k4 < 16; ++k4) {
        float4 w = v[k4];
        w.x *= iv; w.y *= iv; w.z *= iv; w.w *= iv;
        colM[((size_t)b * 16 + k4) * NN + colp] = w;
    }
}

// ---------------------------------------------------------------------------
// K3: GEMM-argmax, column-split across waves (cuts col L2 traffic 4x vs R9).
// Block = 16 rows shared by ALL 4 waves; wave w owns cols t*512+w*128..+127.
//  - cols: only 2 coalesced float4 streams per wave per k4 (vs R9's 8) ->
//    per-CU L2 demand ~32 B/cyc at full VALU, under the 56 B/cyc ceiling.
//  - rows: 16 wave-uniform loads per k4 via readfirstlane'd tokens (scalar
//    path, R3-proven); no DS ops in the loop -> no lgkmcnt mixing.
//  - registers: acc[16][2]=32 + tmax/msk=32 + cv=8 ~ 85 < 128 cap; NO hand
//    double-buffer (R8/R10 lesson -- the allocator spills rather than hold).
//  - ties: running max + (t,j) bitmask; cross-wave merge via 256B LDS.
//  - 1-D grid, b = id&15 -> XCD pinning (FETCH 6.8 MB, L2-resident).
// ---------------------------------------------------------------------------
__global__ __launch_bounds__(TPB, 4) void k_argmax(
    const float* __restrict__ x,      // [B,N,C]
    const float4* __restrict__ colM,  // [B,16,N] float4
    const int*   __restrict__ cntP,
    const int*   __restrict__ cntK,
    const int*   __restrict__ listP,
    const int*   __restrict__ listK,
    float* __restrict__ S,            // [B,N]   zeroed by k_pre
    float* __restrict__ A) {          // [B,N,C] zeroed by k_pre; aliases d_out

    const int b    = blockIdx.x & 15;
    const int tile = blockIdx.x >> 4;
    const int P = cntP[b], K = cntK[b];
    const int base = tile * MROWS;
    if (base >= P) return;

    const int tid = threadIdx.x;
    const int wid = tid >> 6;
    const int lane = tid & 63;

    __shared__ float wm[4][MROWS];

    int rtok[MROWS];
#pragma unroll
    for (int r = 0; r < MROWS; ++r) {
        int rid = base + r;
        int tok = (rid < P) ? listP[b * NN + rid] : 0;
        rtok[r] = __builtin_amdgcn_readfirstlane(tok);
    }
    const float4* x4 = (const float4*)(x + (size_t)b * NN * CC);
    const float4* cm = colM + (size_t)b * 16 * NN;

    float    tmax[MROWS];
    unsigned msk[MROWS];
#pragma unroll
    for (int r = 0; r < MROWS; ++r) { tmax[r] = -3.0e38f; msk[r] = 0u; }

    const int ntiles = (K + 511) >> 9;              // dynamic, <= 4

    for (int t = 0; t < ntiles; ++t) {
        const int cstart = t * 512 + wid * 128;     // this wave's 128-col seg
        if (cstart >= K) break;                     // wave-uniform

        float acc[MROWS][2];
#pragma unroll
        for (int r = 0; r < MROWS; ++r) { acc[r][0] = 0.0f; acc[r][1] = 0.0f; }

#pragma unroll 4
        for (int k4 = 0; k4 < 16; ++k4) {
            const float4* cb = cm + (size_t)k4 * NN + cstart + lane;
            float4 cv0 = cb[0];
            float4 cv1 = cb[64];
#pragma unroll
            for (int r = 0; r < MROWS; ++r) {
                float4 rv = x4[(size_t)rtok[r] * 16 + k4];   // wave-uniform
                acc[r][0] = fmaf(rv.x, cv0.x, fmaf(rv.y, cv0.y,
                            fmaf(rv.z, cv0.z, fmaf(rv.w, cv0.w, acc[r][0]))));
                acc[r][1] = fmaf(rv.x, cv1.x, fmaf(rv.y, cv1.y,
                            fmaf(rv.z, cv1.z, fmaf(rv.w, cv1.w, acc[r][1]))));
            }
        }

        // running max + tie mask (bit = t*2 + j, 8 bits used)
#pragma unroll
        for (int r = 0; r < MROWS; ++r)
#pragma unroll
            for (int j = 0; j < 2; ++j) {
                int colp = cstart + j * 64 + lane;
                float s = (colp < K) ? acc[r][j] : -1.0e30f;
                unsigned bit = 1u << ((t << 1) | j);
                if (s > tmax[r])       { tmax[r] = s; msk[r] = bit; }
                else if (s == tmax[r])  msk[r] |= bit;
            }
    }

    // ---- cross-wave max exchange ----
#pragma unroll
    for (int r = 0; r < MROWS; ++r) {
        float m = tmax[r];
#pragma unroll
        for (int off = 32; off; off >>= 1) m = fmaxf(m, __shfl_xor(m, off, 64));
        if (lane == 0) wm[wid][r] = m;
    }
    __syncthreads();

    // ---- edge emission: each wave emits matches within its col segments ----
    const int nvr = min(MROWS, P - base);
#pragma unroll
    for (int r = 0; r < MROWS; ++r) {
        if (r >= nvr) break;
        float m = fmaxf(fmaxf(wm[0][r], wm[1][r]), fmaxf(wm[2][r], wm[3][r]));
        int src = rtok[r];
        float xv = x[(size_t)(b * NN + src) * CC + lane];
        float sq = xv * xv;
#pragma unroll
        for (int off = 32; off; off >>= 1) sq += __shfl_xor(sq, off, 64);
        float ivr = 1.0f / (sqrtf(sq) + 1e-6f);
        float wgt = expf(m * ivr);
        unsigned long long bal = __ballot(tmax[r] == m && msk[r] != 0u);
        while (bal) {
            int sl = __ffsll(bal) - 1;
            bal &= bal - 1;
            unsigned mm = __shfl(msk[r], sl);
            while (mm) {
                int bit = __ffs(mm) - 1;
                mm &= mm - 1;
                int colp = (bit >> 1) * 512 + wid * 128 + (bit & 1) * 64 + sl;
                int dst = listK[b * NN + colp];
                atomicAdd(&A[(size_t)(b * NN + dst) * CC + lane], wgt * xv);
                if (lane == 0) atomicAdd(&S[b * NN + dst], wgt);
            }
        }
    }
}

// ---------------------------------------------------------------------------
// K4: out = (e*x + A) / (e + S).  A aliases d_out (in-place), float4.
// ---------------------------------------------------------------------------
__global__ __launch_bounds__(TPB) void k_finalize(const float* __restrict__ x,
                                                  const float* __restrict__ S,
                                                  float* __restrict__ out) {
    int i = blockIdx.x * TPB + threadIdx.x;
    int row = i >> 4;
    float inv = 1.0f / (E_CONST + S[row]);
    float4 xv = ((const float4*)x)[i];
    float4 av = ((float4*)out)[i];
    float4 o;
    o.x = (xv.x * E_CONST + av.x) * inv;
    o.y = (xv.y * E_CONST + av.y) * inv;
    o.z = (xv.z * E_CONST + av.z) * inv;
    o.w = (xv.w * E_CONST + av.w) * inv;
    ((float4*)out)[i] = o;
}

// ---------------------------------------------------------------------------
extern "C" void kernel_launch(void* const* d_in, const int* in_sizes, int n_in,
                              void* d_out, int out_size, void* d_ws, size_t ws_size,
                              hipStream_t stream) {
    const float* x    = (const float*)d_in[0];
    const float* keep = (const float*)d_in[2];
    float* out = (float*)d_out;

    // ws: (reserved 128KB) | S 128KB | cnts 128B | listP 128KB | listK 128KB | colM 8MB
    char* ws = (char*)d_ws;
    float* S    = (float*)(ws + (128 << 10));
    int*   cntP = (int*)(ws + (256 << 10));
    int*   cntK = cntP + 16;
    int*   listP = (int*)(ws + (256 << 10) + 128);
    int*   listK = listP + BB * NN;
    float4* colM = (float4*)(ws + (1 << 20));

    k_pre<<<512, TPB, 0, stream>>>(keep, out, S, cntP, cntK, listP, listK);

    dim3 gp2(NN / TPB, BB);
    k_pre2<<<gp2, TPB, 0, stream>>>(x, cntK, listK, colM);

    // 1-D grid: b = id & 15 (XCD pinning), tile = id >> 4.
    k_argmax<<<(NN / MROWS) * BB, TPB, 0, stream>>>(x, colM, cntP, cntK,
                                                    listP, listK, S, out);

    k_finalize<<<(BB * NN * CC / 4) / TPB, TPB, 0, stream>>>(x, S, out);
}

// Round 12
// 183.791 us; speedup vs baseline: 7.6129x; 1.2927x over previous
//
#include <hip/hip_runtime.h>
#include <math.h>

// Problem constants (B,N,C fixed by the reference setup).
#define BB 16
#define NN 2048
#define CC 64
#define TPB 256
#define MROWS 16          // pruned rows per block (4 waves x 4 rows)
#define RPW 4             // rows per wave
#define E_CONST 2.71828182845904523536f

// ---------------------------------------------------------------------------
// K_pre (fused): all 512 blocks zero their 16 KB slice of out (the A
// accumulator).  Blocks 0..BB-1 additionally: ballot-compaction for batch b,
// zero S[b,:], then build colM[b] (normalized kept cols, k-quad-minor).
// ---------------------------------------------------------------------------
__global__ __launch_bounds__(TPB) void k_pre(const float* __restrict__ x,
                                             const float* __restrict__ keep,
                                             float* __restrict__ outz,
                                             float* __restrict__ S,
                                             int* __restrict__ cntP,
                                             int* __restrict__ cntK,
                                             int* __restrict__ listP,
                                             int* __restrict__ listK,
                                             float4* __restrict__ colM) {
    const int tid = threadIdx.x, lane = tid & 63;

    float4* o4 = (float4*)outz + (size_t)blockIdx.x * 1024;
    float4 z = {0.0f, 0.0f, 0.0f, 0.0f};
#pragma unroll
    for (int i = 0; i < 4; ++i) o4[i * TPB + tid] = z;

    const int b = blockIdx.x;
    if (b >= BB) return;

    __shared__ int cP, cK;
    if (tid == 0) { cP = 0; cK = 0; }
    __syncthreads();
    for (int i = tid; i < NN; i += TPB) S[b * NN + i] = 0.0f;
    const unsigned long long lt = (lane == 63) ? 0x7fffffffffffffffull
                                               : ((1ull << lane) - 1ull);
#pragma unroll
    for (int it = 0; it < NN / TPB; ++it) {
        int n = it * TPB + tid;
        bool kp = keep[b * NN + n] != 0.0f;
        unsigned long long mk = __ballot(kp);
        int nk = __popcll(mk);
        int bk = 0, bp = 0;
        if (lane == 0) {
            bk = atomicAdd(&cK, nk);
            bp = atomicAdd(&cP, 64 - nk);
        }
        bk = __shfl(bk, 0); bp = __shfl(bp, 0);
        int pk = __popcll(mk & lt);
        if (kp) listK[b * NN + bk + pk] = n;
        else    listP[b * NN + bp + (lane - pk)] = n;
    }
    __syncthreads();
    if (tid == 0) { cntP[b] = cP; cntK[b] = cK; }
    __syncthreads();

    // ---- build colM for this batch (fused old k_pre2) ----
    const int K = cK;
    const float4* x4 = (const float4*)(x + (size_t)b * NN * CC);
#pragma unroll
    for (int it = 0; it < NN / TPB; ++it) {
        int colp = it * TPB + tid;
        bool ok = colp < K;
        int tok = ok ? listK[b * NN + colp] : 0;
        float4 v[16];
        float sq = 0.0f;
#pragma unroll
        for (int k4 = 0; k4 < 16; ++k4) {
            v[k4] = x4[(size_t)tok * 16 + k4];
            sq += v[k4].x * v[k4].x + v[k4].y * v[k4].y
                + v[k4].z * v[k4].z + v[k4].w * v[k4].w;
        }
        float iv = ok ? 1.0f / (sqrtf(sq) + 1e-6f) : 0.0f;
#pragma unroll
        for (int k4 = 0; k4 < 16; ++k4) {
            float4 w = v[k4];
            w.x *= iv; w.y *= iv; w.z *= iv; w.w *= iv;
            colM[((size_t)b * 16 + k4) * NN + colp] = w;
        }
    }
}

// ---------------------------------------------------------------------------
// K3: GEMM-argmax -- the PROVEN R9 kernel (73 us, VGPR 60, no spill), with
// one bounded change: k4 unroll 2 -> 4, giving the compiler's scheduler 2x
// more independent col loads to pipeline within the 128-VGPR cap.  No
// hand-named buffers (R8/R10/R11 spill lessons).
// Block = 4 waves x 4 rows; each wave sweeps ALL kept cols (512-col tiles).
//  - 1-D grid, b = id&15 -> XCD pinning (FETCH ~6.8 MB, colM L2-resident).
// ---------------------------------------------------------------------------
__global__ __launch_bounds__(TPB, 4) void k_argmax(
    const float* __restrict__ x,      // [B,N,C]
    const float4* __restrict__ colM,  // [B,16,N] float4
    const int*   __restrict__ cntP,
    const int*   __restrict__ cntK,
    const int*   __restrict__ listP,
    const int*   __restrict__ listK,
    float* __restrict__ S,            // [B,N]   zeroed by k_pre
    float* __restrict__ A) {          // [B,N,C] zeroed by k_pre; aliases d_out

    const int b    = blockIdx.x & 15;
    const int tile = blockIdx.x >> 4;
    const int P = cntP[b], K = cntK[b];
    const int base = tile * MROWS;
    if (base >= P) return;

    const int tid = threadIdx.x;
    const int wid = tid >> 6;
    const int lane = tid & 63;

    int rtok[RPW];
#pragma unroll
    for (int r = 0; r < RPW; ++r) {
        int rid = base + wid * RPW + r;
        int tok = (rid < P) ? listP[b * NN + rid] : 0;
        rtok[r] = __builtin_amdgcn_readfirstlane(tok);
    }
    const float4* x4 = (const float4*)(x + (size_t)b * NN * CC);
    const float4* cm = colM + (size_t)b * 16 * NN;

    float    tmax[RPW];
    unsigned msk[RPW];
#pragma unroll
    for (int r = 0; r < RPW; ++r) { tmax[r] = -3.0e38f; msk[r] = 0u; }

    const int ntiles = (K + 511) >> 9;              // dynamic, <= 4

    for (int t = 0; t < ntiles; ++t) {
        const int cstart = t * 512;

        float acc[RPW][8];
#pragma unroll
        for (int r = 0; r < RPW; ++r)
#pragma unroll
            for (int j = 0; j < 8; ++j) acc[r][j] = 0.0f;

#pragma unroll 4
        for (int k4 = 0; k4 < 16; ++k4) {
            float4 rv[RPW];
#pragma unroll
            for (int r = 0; r < RPW; ++r)           // wave-uniform 16B loads
                rv[r] = x4[(size_t)rtok[r] * 16 + k4];
            const float4* cmk = cm + (size_t)k4 * NN + cstart + lane;
            float4 cv[8];
#pragma unroll
            for (int j = 0; j < 8; ++j)             // coalesced b128 streams
                cv[j] = cmk[j * 64];
#pragma unroll
            for (int r = 0; r < RPW; ++r)
#pragma unroll
                for (int j = 0; j < 8; ++j)
                    acc[r][j] = fmaf(rv[r].x, cv[j].x,
                                fmaf(rv[r].y, cv[j].y,
                                fmaf(rv[r].z, cv[j].z,
                                fmaf(rv[r].w, cv[j].w, acc[r][j]))));
        }

#pragma unroll
        for (int r = 0; r < RPW; ++r)
#pragma unroll
            for (int j = 0; j < 8; ++j) {
                int colp = cstart + j * 64 + lane;
                float s = (colp < K) ? acc[r][j] : -1.0e30f;
                unsigned bit = 1u << ((t << 3) | j);
                if (s > tmax[r])       { tmax[r] = s; msk[r] = bit; }
                else if (s == tmax[r])  msk[r] |= bit;
            }
    }

    // ---- edge emission: per wave, per valid row ----
    int nvr = P - base - wid * RPW;
    for (int r = 0; r < RPW; ++r) {
        if (r >= nvr) break;
        float m = tmax[r];
#pragma unroll
        for (int off = 32; off; off >>= 1) m = fmaxf(m, __shfl_xor(m, off, 64));
        int src = rtok[r];
        float xv = x[(size_t)(b * NN + src) * CC + lane];
        float sq = xv * xv;
#pragma unroll
        for (int off = 32; off; off >>= 1) sq += __shfl_xor(sq, off, 64);
        float ivr = 1.0f / (sqrtf(sq) + 1e-6f);
        float wgt = expf(m * ivr);
        unsigned long long bal = __ballot(tmax[r] == m && msk[r] != 0u);
        while (bal) {
            int sl = __ffsll(bal) - 1;
            bal &= bal - 1;
            unsigned mm = __shfl(msk[r], sl);
            while (mm) {
                int bit = __ffs(mm) - 1;
                mm &= mm - 1;
                int colp = ((bit >> 3) * 512) + ((bit & 7) * 64) + sl;
                int dst = listK[b * NN + colp];
                atomicAdd(&A[(size_t)(b * NN + dst) * CC + lane], wgt * xv);
                if (lane == 0) atomicAdd(&S[b * NN + dst], wgt);
            }
        }
    }
}

// ---------------------------------------------------------------------------
// K4: out = (e*x + A) / (e + S).  A aliases d_out (in-place), float4.
// ---------------------------------------------------------------------------
__global__ __launch_bounds__(TPB) void k_finalize(const float* __restrict__ x,
                                                  const float* __restrict__ S,
                                                  float* __restrict__ out) {
    int i = blockIdx.x * TPB + threadIdx.x;
    int row = i >> 4;
    float inv = 1.0f / (E_CONST + S[row]);
    float4 xv = ((const float4*)x)[i];
    float4 av = ((float4*)out)[i];
    float4 o;
    o.x = (xv.x * E_CONST + av.x) * inv;
    o.y = (xv.y * E_CONST + av.y) * inv;
    o.z = (xv.z * E_CONST + av.z) * inv;
    o.w = (xv.w * E_CONST + av.w) * inv;
    ((float4*)out)[i] = o;
}

// ---------------------------------------------------------------------------
extern "C" void kernel_launch(void* const* d_in, const int* in_sizes, int n_in,
                              void* d_out, int out_size, void* d_ws, size_t ws_size,
                              hipStream_t stream) {
    const float* x    = (const float*)d_in[0];
    const float* keep = (const float*)d_in[2];
    float* out = (float*)d_out;

    // ws: (reserved 128KB) | S 128KB | cnts 128B | listP 128KB | listK 128KB | colM 8MB
    char* ws = (char*)d_ws;
    float* S    = (float*)(ws + (128 << 10));
    int*   cntP = (int*)(ws + (256 << 10));
    int*   cntK = cntP + 16;
    int*   listP = (int*)(ws + (256 << 10) + 128);
    int*   listK = listP + BB * NN;
    float4* colM = (float4*)(ws + (1 << 20));

    k_pre<<<512, TPB, 0, stream>>>(x, keep, out, S, cntP, cntK,
                                   listP, listK, colM);

    // 1-D grid: b = id & 15 (XCD pinning), tile = id >> 4.
    k_argmax<<<(NN / MROWS) * BB, TPB, 0, stream>>>(x, colM, cntP, cntK,
                                                    listP, listK, S, out);

    k_finalize<<<(BB * NN * CC / 4) / TPB, TPB, 0, stream>>>(x, S, out);
}

// Round 13
// 147.473 us; speedup vs baseline: 9.4877x; 1.2463x over previous
//
#include <hip/hip_runtime.h>
#include <math.h>

// Problem constants (B,N,C fixed by the reference setup).
#define BB 16
#define NN 2048
#define CC 64
#define TPB 256
#define MROWS 16          // pruned rows per block (4 waves x 4 rows)
#define RPW 4             // rows per wave
#define E_CONST 2.71828182845904523536f

// ---------------------------------------------------------------------------
// K_pre: zero the A accumulator (d_out) everywhere; blocks 0..BB-1 also run
// ballot-based kept/pruned compaction for batch b and zero S[b,:].
// ---------------------------------------------------------------------------
__global__ __launch_bounds__(TPB) void k_pre(const float* __restrict__ keep,
                                             float* __restrict__ outz,
                                             float* __restrict__ S,
                                             int* __restrict__ cntP,
                                             int* __restrict__ cntK,
                                             int* __restrict__ listP,
                                             int* __restrict__ listK) {
    const int tid = threadIdx.x, lane = tid & 63;

    float4* o4 = (float4*)outz + (size_t)blockIdx.x * 1024;
    float4 z = {0.0f, 0.0f, 0.0f, 0.0f};
#pragma unroll
    for (int i = 0; i < 4; ++i) o4[i * TPB + tid] = z;

    const int b = blockIdx.x;
    if (b >= BB) return;

    __shared__ int cP, cK;
    if (tid == 0) { cP = 0; cK = 0; }
    __syncthreads();
    for (int i = tid; i < NN; i += TPB) S[b * NN + i] = 0.0f;
    const unsigned long long lt = (lane == 63) ? 0x7fffffffffffffffull
                                               : ((1ull << lane) - 1ull);
#pragma unroll
    for (int it = 0; it < NN / TPB; ++it) {
        int n = it * TPB + tid;
        bool kp = keep[b * NN + n] != 0.0f;
        unsigned long long mk = __ballot(kp);
        int nk = __popcll(mk);
        int bk = 0, bp = 0;
        if (lane == 0) {
            bk = atomicAdd(&cK, nk);
            bp = atomicAdd(&cP, 64 - nk);
        }
        bk = __shfl(bk, 0); bp = __shfl(bp, 0);
        int pk = __popcll(mk & lt);
        if (kp) listK[b * NN + bk + pk] = n;
        else    listP[b * NN + bp + (lane - pk)] = n;
    }
    __syncthreads();
    if (tid == 0) { cntP[b] = cP; cntK[b] = cK; }
}

// ---------------------------------------------------------------------------
// K_pre2: build colM[b][k4][colp] float4 = k-quad of kept column colp, scaled
// by its inverse L2 norm (computed inline); zeros for colp >= K.
// ---------------------------------------------------------------------------
__global__ __launch_bounds__(TPB) void k_pre2(const float* __restrict__ x,
                                              const int* __restrict__ cntK,
                                              const int* __restrict__ listK,
                                              float4* __restrict__ colM) {
    const int b = blockIdx.y;
    const int colp = blockIdx.x * TPB + threadIdx.x;
    const int K = cntK[b];
    bool ok = colp < K;
    int tok = ok ? listK[b * NN + colp] : 0;
    const float4* x4 = (const float4*)(x + (size_t)b * NN * CC);
    float4 v[16];
    float sq = 0.0f;
#pragma unroll
    for (int k4 = 0; k4 < 16; ++k4) {
        v[k4] = x4[(size_t)tok * 16 + k4];
        sq += v[k4].x * v[k4].x + v[k4].y * v[k4].y
            + v[k4].z * v[k4].z + v[k4].w * v[k4].w;
    }
    float iv = ok ? 1.0f / (sqrtf(sq) + 1e-6f) : 0.0f;
#pragma unroll
    for (int k4 = 0; k4 < 16; ++k4) {
        float4 w = v[k4];
        w.x *= iv; w.y *= iv; w.z *= iv; w.w *= iv;
        colM[((size_t)b * 16 + k4) * NN + colp] = w;
    }
}

// ---------------------------------------------------------------------------
// K3: GEMM-argmax (the R9 optimum, restored exactly).
// Block = 4 waves x 4 rows; each wave sweeps ALL kept cols (512-col tiles).
//  - acc[4][8] = 32 VGPR + cv[8] = 32 VGPR: the one tile shape this
//    allocator schedules without spilling (VGPR 60) or serializing.
//  - unroll 2 (unroll 4 regressed: VGPR 52, +42% time -- R12).
//  - rows: 4 wave-uniform float4 loads per k4 (L1-resident).
//  - 1-D grid, b = id&15 -> XCD pinning (FETCH ~6.8 MB, colM L2-resident).
//  - NO hand double-buffer / SGPR tricks (R6/R8/R10/R11 all spilled).
// ---------------------------------------------------------------------------
__global__ __launch_bounds__(TPB, 4) void k_argmax(
    const float* __restrict__ x,      // [B,N,C]
    const float4* __restrict__ colM,  // [B,16,N] float4
    const int*   __restrict__ cntP,
    const int*   __restrict__ cntK,
    const int*   __restrict__ listP,
    const int*   __restrict__ listK,
    float* __restrict__ S,            // [B,N]   zeroed by k_pre
    float* __restrict__ A) {          // [B,N,C] zeroed by k_pre; aliases d_out

    const int b    = blockIdx.x & 15;
    const int tile = blockIdx.x >> 4;
    const int P = cntP[b], K = cntK[b];
    const int base = tile * MROWS;
    if (base >= P) return;

    const int tid = threadIdx.x;
    const int wid = tid >> 6;
    const int lane = tid & 63;

    int rtok[RPW];
#pragma unroll
    for (int r = 0; r < RPW; ++r) {
        int rid = base + wid * RPW + r;
        int tok = (rid < P) ? listP[b * NN + rid] : 0;
        rtok[r] = __builtin_amdgcn_readfirstlane(tok);
    }
    const float4* x4 = (const float4*)(x + (size_t)b * NN * CC);
    const float4* cm = colM + (size_t)b * 16 * NN;

    float    tmax[RPW];
    unsigned msk[RPW];
#pragma unroll
    for (int r = 0; r < RPW; ++r) { tmax[r] = -3.0e38f; msk[r] = 0u; }

    const int ntiles = (K + 511) >> 9;              // dynamic, <= 4

    for (int t = 0; t < ntiles; ++t) {
        const int cstart = t * 512;

        float acc[RPW][8];
#pragma unroll
        for (int r = 0; r < RPW; ++r)
#pragma unroll
            for (int j = 0; j < 8; ++j) acc[r][j] = 0.0f;

#pragma unroll 2
        for (int k4 = 0; k4 < 16; ++k4) {
            float4 rv[RPW];
#pragma unroll
            for (int r = 0; r < RPW; ++r)           // wave-uniform 16B loads
                rv[r] = x4[(size_t)rtok[r] * 16 + k4];
            const float4* cmk = cm + (size_t)k4 * NN + cstart + lane;
            float4 cv[8];
#pragma unroll
            for (int j = 0; j < 8; ++j)             // coalesced b128 streams
                cv[j] = cmk[j * 64];
#pragma unroll
            for (int r = 0; r < RPW; ++r)
#pragma unroll
                for (int j = 0; j < 8; ++j)
                    acc[r][j] = fmaf(rv[r].x, cv[j].x,
                                fmaf(rv[r].y, cv[j].y,
                                fmaf(rv[r].z, cv[j].z,
                                fmaf(rv[r].w, cv[j].w, acc[r][j]))));
        }

#pragma unroll
        for (int r = 0; r < RPW; ++r)
#pragma unroll
            for (int j = 0; j < 8; ++j) {
                int colp = cstart + j * 64 + lane;
                float s = (colp < K) ? acc[r][j] : -1.0e30f;
                unsigned bit = 1u << ((t << 3) | j);
                if (s > tmax[r])       { tmax[r] = s; msk[r] = bit; }
                else if (s == tmax[r])  msk[r] |= bit;
            }
    }

    // ---- edge emission: per wave, per valid row ----
    int nvr = P - base - wid * RPW;
    for (int r = 0; r < RPW; ++r) {
        if (r >= nvr) break;
        float m = tmax[r];
#pragma unroll
        for (int off = 32; off; off >>= 1) m = fmaxf(m, __shfl_xor(m, off, 64));
        int src = rtok[r];
        float xv = x[(size_t)(b * NN + src) * CC + lane];
        float sq = xv * xv;
#pragma unroll
        for (int off = 32; off; off >>= 1) sq += __shfl_xor(sq, off, 64);
        float ivr = 1.0f / (sqrtf(sq) + 1e-6f);
        float wgt = expf(m * ivr);
        unsigned long long bal = __ballot(tmax[r] == m && msk[r] != 0u);
        while (bal) {
            int sl = __ffsll(bal) - 1;
            bal &= bal - 1;
            unsigned mm = __shfl(msk[r], sl);
            while (mm) {
                int bit = __ffs(mm) - 1;
                mm &= mm - 1;
                int colp = ((bit >> 3) * 512) + ((bit & 7) * 64) + sl;
                int dst = listK[b * NN + colp];
                atomicAdd(&A[(size_t)(b * NN + dst) * CC + lane], wgt * xv);
                if (lane == 0) atomicAdd(&S[b * NN + dst], wgt);
            }
        }
    }
}

// ---------------------------------------------------------------------------
// K4: out = (e*x + A) / (e + S).  A aliases d_out (in-place), float4.
// ---------------------------------------------------------------------------
__global__ __launch_bounds__(TPB) void k_finalize(const float* __restrict__ x,
                                                  const float* __restrict__ S,
                                                  float* __restrict__ out) {
    int i = blockIdx.x * TPB + threadIdx.x;
    int row = i >> 4;
    float inv = 1.0f / (E_CONST + S[row]);
    float4 xv = ((const float4*)x)[i];
    float4 av = ((float4*)out)[i];
    float4 o;
    o.x = (xv.x * E_CONST + av.x) * inv;
    o.y = (xv.y * E_CONST + av.y) * inv;
    o.z = (xv.z * E_CONST + av.z) * inv;
    o.w = (xv.w * E_CONST + av.w) * inv;
    ((float4*)out)[i] = o;
}

// ---------------------------------------------------------------------------
extern "C" void kernel_launch(void* const* d_in, const int* in_sizes, int n_in,
                              void* d_out, int out_size, void* d_ws, size_t ws_size,
                              hipStream_t stream) {
    const float* x    = (const float*)d_in[0];
    const float* keep = (const float*)d_in[2];
    float* out = (float*)d_out;

    // ws: (reserved 128KB) | S 128KB | cnts 128B | listP 128KB | listK 128KB | colM 8MB
    char* ws = (char*)d_ws;
    float* S    = (float*)(ws + (128 << 10));
    int*   cntP = (int*)(ws + (256 << 10));
    int*   cntK = cntP + 16;
    int*   listP = (int*)(ws + (256 << 10) + 128);
    int*   listK = listP + BB * NN;
    float4* colM = (float4*)(ws + (1 << 20));

    k_pre<<<512, TPB, 0, stream>>>(keep, out, S, cntP, cntK, listP, listK);

    dim3 gp2(NN / TPB, BB);
    k_pre2<<<gp2, TPB, 0, stream>>>(x, cntK, listK, colM);

    // 1-D grid: b = id & 15 (XCD pinning), tile = id >> 4.
    k_argmax<<<(NN / MROWS) * BB, TPB, 0, stream>>>(x, colM, cntP, cntK,
                                                    listP, listK, S, out);

    k_finalize<<<(BB * NN * CC / 4) / TPB, TPB, 0, stream>>>(x, S, out);
}